// Round 2
// baseline (176.744 us; speedup 1.0000x reference)
//
#include <hip/hip_runtime.h>

namespace {
constexpr int N_ELEMS = 262144;
constexpr int N_NODES = 263169;
constexpr int N_WORK  = N_ELEMS * 4;   // one thread per (element, ip)

// folded material constants (fp32, match reference math)
constexpr float GC_2L0  = 0.09f;                 // G_C / (2*L_0)
constexpr float L0SQ    = 0.015f * 0.015f;
constexpr float MU_     = 80.76923076923077f;    // E/(2(1+nu))
constexpr float K_MOD   = 175.0f;                // lam + 2mu/3 (exact)
constexpr float PENALTY = 1799.82f;              // G_C/L_0*(1/PF_TOL^2-1)
}

__device__ __forceinline__ float waveReduce(float x) {
#pragma unroll
    for (int off = 32; off; off >>= 1) x += __shfl_down(x, off, 64);
    return x;
}

__global__ __launch_bounds__(256) void fused_energy(
    const float* __restrict__ u, const float* __restrict__ v,
    const float* __restrict__ c, const float* __restrict__ prev_c,
    const int* __restrict__ conn,
    const float* __restrict__ Nf, const float* __restrict__ dNdx,
    const float* __restrict__ B, const float* __restrict__ vol,
    float* __restrict__ out)
{
    const int tid = blockIdx.x * blockDim.x + threadIdx.x;
    float Eel = 0.f, Efr = 0.f, Eirr = 0.f;

    if (tid < N_WORK) {
        const int e  = tid >> 2;
        const int ip = tid & 3;

        const int4 cn = *reinterpret_cast<const int4*>(conn + 4ll * e);
        const float c0 = c[cn.x], c1 = c[cn.y], c2 = c[cn.z], c3 = c[cn.w];
        const float uv0 = u[cn.x], uv1 = v[cn.x];
        const float uv2 = u[cn.y], uv3 = v[cn.y];
        const float uv4 = u[cn.z], uv5 = v[cn.z];
        const float uv6 = u[cn.w], uv7 = v[cn.w];
        const float o0 = 1.f - c0, o1 = 1.f - c1, o2 = 1.f - c2, o3 = 1.f - c3;

        // per-(e,ip) contiguous chunks; consecutive lanes sweep dense regions
        const float4  Nr = *reinterpret_cast<const float4*>(Nf + 16ll * e + 4 * ip);
        const float4* Dp = reinterpret_cast<const float4*>(dNdx + 32ll * e + 8 * ip);
        const float4  dx = Dp[0], dy = Dp[1];
        const float4* Bp = reinterpret_cast<const float4*>(B + 96ll * e + 24 * ip);
        const float4 b0 = Bp[0], b1 = Bp[1], b2 = Bp[2];
        const float4 b3 = Bp[3], b4 = Bp[4], b5 = Bp[5];
        const float vip = vol[4ll * e + ip];

        // degradation + fracture density
        const float omc = Nr.x * o0 + Nr.y * o1 + Nr.z * o2 + Nr.w * o3;
        const float g   = omc * omc;
        const float cip = 1.f - omc;
        const float gx  = dx.x * c0 + dx.y * c1 + dx.z * c2 + dx.w * c3;
        const float gy  = dy.x * c0 + dy.y * c1 + dy.z * c2 + dy.w * c3;
        Efr = GC_2L0 * (cip * cip + L0SQ * (gx * gx + gy * gy)) * vip;

        // strain via B (rows: exx = floats 0..7, eyy = 8..15, gxy = 16..23)
        const float exx = b0.x * uv0 + b0.y * uv1 + b0.z * uv2 + b0.w * uv3
                        + b1.x * uv4 + b1.y * uv5 + b1.z * uv6 + b1.w * uv7;
        const float eyy = b2.x * uv0 + b2.y * uv1 + b2.z * uv2 + b2.w * uv3
                        + b3.x * uv4 + b3.y * uv5 + b3.z * uv6 + b3.w * uv7;
        const float gxy = b4.x * uv0 + b4.y * uv1 + b4.z * uv2 + b4.w * uv3
                        + b5.x * uv4 + b5.y * uv5 + b5.z * uv6 + b5.w * uv7;
        const float exy = 0.5f * gxy;
        const float tr  = exx + eyy;
        const float tr3 = tr * (1.f / 3.f);
        const float dxx = exx - tr3, dyy = eyy - tr3, dzz = -tr3;
        const float dev2 = dxx * dxx + dyy * dyy + dzz * dzz + 2.f * exy * exy;
        const float trp = fmaxf(tr, 0.f), trn = fminf(tr, 0.f);
        const float psip = 0.5f * K_MOD * trp * trp + MU_ * dev2;
        const float psim = 0.5f * K_MOD * trn * trn;
        Eel = (psip * g + psim) * vip;
    }

    // fused irreversibility penalty: thread tid handles node tid
    if (tid < N_NODES) {
        float d = fmaxf(prev_c[tid] - c[tid], 0.f);
        Eirr = 0.5f * PENALTY * d * d;
    }

    Eel  = waveReduce(Eel);
    Efr  = waveReduce(Efr);
    Eirr = waveReduce(Eirr);
    __shared__ float sE[4], sF[4], sI[4];
    const int lane = threadIdx.x & 63, wid = threadIdx.x >> 6;
    if (lane == 0) { sE[wid] = Eel; sF[wid] = Efr; sI[wid] = Eirr; }
    __syncthreads();
    if (threadIdx.x == 0) {
        atomicAdd(&out[0], sE[0] + sE[1] + sE[2] + sE[3]);
        atomicAdd(&out[1], sF[0] + sF[1] + sF[2] + sF[3]);
        atomicAdd(&out[2], sI[0] + sI[1] + sI[2] + sI[3]);
    }
}

extern "C" void kernel_launch(void* const* d_in, const int* in_sizes, int n_in,
                              void* d_out, int out_size, void* d_ws, size_t ws_size,
                              hipStream_t stream) {
    const float* u      = (const float*)d_in[0];
    const float* v      = (const float*)d_in[1];
    const float* c      = (const float*)d_in[2];
    const float* prev_c = (const float*)d_in[3];
    const int*   conn   = (const int*)d_in[4];
    const float* Nf     = (const float*)d_in[5];
    const float* dNdx   = (const float*)d_in[6];
    const float* B      = (const float*)d_in[7];
    const float* vol    = (const float*)d_in[8];
    float* out = (float*)d_out;

    hipMemsetAsync(out, 0, 3 * sizeof(float), stream);

    fused_energy<<<(N_WORK + 255) / 256, 256, 0, stream>>>(
        u, v, c, prev_c, conn, Nf, dNdx, B, vol, out);
}

// Round 4
// 105.041 us; speedup vs baseline: 1.6826x; 1.6826x over previous
//
#include <hip/hip_runtime.h>

namespace {
constexpr int N_ELEMS  = 262144;
constexpr int N_NODES  = 263169;
constexpr int N_WORK   = N_ELEMS * 4;     // 1048576 (element, ip) units
constexpr int NTHREADS = N_WORK / 2;      // 524288 — each thread does 2 units
constexpr int BLK      = 256;

// folded material constants (fp32, match reference math)
constexpr float GC_2L0  = 0.09f;                 // G_C / (2*L_0)
constexpr float L0SQ    = 0.015f * 0.015f;
constexpr float MU_     = 80.76923076923077f;    // E/(2(1+nu))
constexpr float K_MOD   = 175.0f;                // lam + 2mu/3 (exact)
constexpr float PENALTY = 1799.82f;              // G_C/L_0*(1/PF_TOL^2-1)
}

typedef float vfloat4 __attribute__((ext_vector_type(4)));
typedef int   vint4   __attribute__((ext_vector_type(4)));

__device__ __forceinline__ vfloat4 ntload4f(const float* p) {
    return __builtin_nontemporal_load(reinterpret_cast<const vfloat4*>(p));
}
__device__ __forceinline__ vint4 ntload4i(const int* p) {
    return __builtin_nontemporal_load(reinterpret_cast<const vint4*>(p));
}
__device__ __forceinline__ float ntloadf(const float* p) {
    return __builtin_nontemporal_load(p);
}

__device__ __forceinline__ float waveReduce(float x) {
#pragma unroll
    for (int off = 32; off; off >>= 1) x += __shfl_down(x, off, 64);
    return x;
}

__global__ __launch_bounds__(256) void fused_energy(
    const float* __restrict__ u, const float* __restrict__ v,
    const float* __restrict__ c, const float* __restrict__ prev_c,
    const int* __restrict__ conn,
    const float* __restrict__ Nf, const float* __restrict__ dNdx,
    const float* __restrict__ B, const float* __restrict__ vol,
    float* __restrict__ out)
{
    const int tid = blockIdx.x * blockDim.x + threadIdx.x;

    const int u0 = tid;                 // unit 0
    const int u1 = tid + NTHREADS;      // unit 1 (always < N_WORK)
    const int e0 = u0 >> 2, ip0 = u0 & 3;
    const int e1 = u1 >> 2, ip1 = u1 & 3;

    // ---- phase A: issue ALL independent loads up front ------------------
    const vint4 cn0 = ntload4i(conn + 4ll * e0);
    const vint4 cn1 = ntload4i(conn + 4ll * e1);

    const vfloat4 Nr0 = ntload4f(Nf + 16ll * e0 + 4 * ip0);
    const vfloat4 Nr1 = ntload4f(Nf + 16ll * e1 + 4 * ip1);

    const float* Dp0 = dNdx + 32ll * e0 + 8 * ip0;
    const float* Dp1 = dNdx + 32ll * e1 + 8 * ip1;
    const vfloat4 dxa = ntload4f(Dp0), dya = ntload4f(Dp0 + 4);
    const vfloat4 dxb = ntload4f(Dp1), dyb = ntload4f(Dp1 + 4);

    const float* Bp0 = B + 96ll * e0 + 24 * ip0;
    const float* Bp1 = B + 96ll * e1 + 24 * ip1;
    const vfloat4 a0 = ntload4f(Bp0 +  0), a1 = ntload4f(Bp0 +  4), a2 = ntload4f(Bp0 +  8);
    const vfloat4 a3 = ntload4f(Bp0 + 12), a4 = ntload4f(Bp0 + 16), a5 = ntload4f(Bp0 + 20);
    const vfloat4 b0 = ntload4f(Bp1 +  0), b1 = ntload4f(Bp1 +  4), b2 = ntload4f(Bp1 +  8);
    const vfloat4 b3 = ntload4f(Bp1 + 12), b4 = ntload4f(Bp1 + 16), b5 = ntload4f(Bp1 + 20);

    const float vipa = ntloadf(vol + 4ll * e0 + ip0);
    const float vipb = ntloadf(vol + 4ll * e1 + ip1);

    // node penalty (independent, cached path)
    float Eirr = 0.f;
    if (tid < N_NODES) {
        float d = fmaxf(prev_c[tid] - c[tid], 0.f);
        Eirr = 0.5f * PENALTY * d * d;
    }

    // ---- gathers (depend only on cn0/cn1; all 24 batched) ---------------
    const float ca0 = c[cn0.x], ca1 = c[cn0.y], ca2 = c[cn0.z], ca3 = c[cn0.w];
    const float cb0 = c[cn1.x], cb1 = c[cn1.y], cb2 = c[cn1.z], cb3 = c[cn1.w];
    const float ua0 = u[cn0.x], va0 = v[cn0.x];
    const float ua1 = u[cn0.y], va1 = v[cn0.y];
    const float ua2 = u[cn0.z], va2 = v[cn0.z];
    const float ua3 = u[cn0.w], va3 = v[cn0.w];
    const float ub0 = u[cn1.x], vb0 = v[cn1.x];
    const float ub1 = u[cn1.y], vb1 = v[cn1.y];
    const float ub2 = u[cn1.z], vb2 = v[cn1.z];
    const float ub3 = u[cn1.w], vb3 = v[cn1.w];

    // ---- phase B: compute ----------------------------------------------
    float Eel = 0.f, Efr = 0.f;
    {   // unit 0
        const float o0 = 1.f - ca0, o1 = 1.f - ca1, o2 = 1.f - ca2, o3 = 1.f - ca3;
        const float omc = Nr0.x * o0 + Nr0.y * o1 + Nr0.z * o2 + Nr0.w * o3;
        const float g = omc * omc, cip = 1.f - omc;
        const float gx = dxa.x * ca0 + dxa.y * ca1 + dxa.z * ca2 + dxa.w * ca3;
        const float gy = dya.x * ca0 + dya.y * ca1 + dya.z * ca2 + dya.w * ca3;
        Efr += GC_2L0 * (cip * cip + L0SQ * (gx * gx + gy * gy)) * vipa;

        const float exx = a0.x * ua0 + a0.y * va0 + a0.z * ua1 + a0.w * va1
                        + a1.x * ua2 + a1.y * va2 + a1.z * ua3 + a1.w * va3;
        const float eyy = a2.x * ua0 + a2.y * va0 + a2.z * ua1 + a2.w * va1
                        + a3.x * ua2 + a3.y * va2 + a3.z * ua3 + a3.w * va3;
        const float gxy = a4.x * ua0 + a4.y * va0 + a4.z * ua1 + a4.w * va1
                        + a5.x * ua2 + a5.y * va2 + a5.z * ua3 + a5.w * va3;
        const float exy = 0.5f * gxy;
        const float tr = exx + eyy, tr3 = tr * (1.f / 3.f);
        const float dxx = exx - tr3, dyy = eyy - tr3, dzz = -tr3;
        const float dev2 = dxx * dxx + dyy * dyy + dzz * dzz + 2.f * exy * exy;
        const float trp = fmaxf(tr, 0.f), trn = fminf(tr, 0.f);
        Eel += ((0.5f * K_MOD * trp * trp + MU_ * dev2) * g
                + 0.5f * K_MOD * trn * trn) * vipa;
    }
    {   // unit 1
        const float o0 = 1.f - cb0, o1 = 1.f - cb1, o2 = 1.f - cb2, o3 = 1.f - cb3;
        const float omc = Nr1.x * o0 + Nr1.y * o1 + Nr1.z * o2 + Nr1.w * o3;
        const float g = omc * omc, cip = 1.f - omc;
        const float gx = dxb.x * cb0 + dxb.y * cb1 + dxb.z * cb2 + dxb.w * cb3;
        const float gy = dyb.x * cb0 + dyb.y * cb1 + dyb.z * cb2 + dyb.w * cb3;
        Efr += GC_2L0 * (cip * cip + L0SQ * (gx * gx + gy * gy)) * vipb;

        const float exx = b0.x * ub0 + b0.y * vb0 + b0.z * ub1 + b0.w * vb1
                        + b1.x * ub2 + b1.y * vb2 + b1.z * ub3 + b1.w * vb3;
        const float eyy = b2.x * ub0 + b2.y * vb0 + b2.z * ub1 + b2.w * vb1
                        + b3.x * ub2 + b3.y * vb2 + b3.z * ub3 + b3.w * vb3;
        const float gxy = b4.x * ub0 + b4.y * vb0 + b4.z * ub1 + b4.w * vb1
                        + b5.x * ub2 + b5.y * vb2 + b5.z * ub3 + b5.w * vb3;
        const float exy = 0.5f * gxy;
        const float tr = exx + eyy, tr3 = tr * (1.f / 3.f);
        const float dxx = exx - tr3, dyy = eyy - tr3, dzz = -tr3;
        const float dev2 = dxx * dxx + dyy * dyy + dzz * dzz + 2.f * exy * exy;
        const float trp = fmaxf(tr, 0.f), trn = fminf(tr, 0.f);
        Eel += ((0.5f * K_MOD * trp * trp + MU_ * dev2) * g
                + 0.5f * K_MOD * trn * trn) * vipb;
    }

    // ---- reductions ------------------------------------------------------
    Eel  = waveReduce(Eel);
    Efr  = waveReduce(Efr);
    Eirr = waveReduce(Eirr);
    __shared__ float sE[4], sF[4], sI[4];
    const int lane = threadIdx.x & 63, wid = threadIdx.x >> 6;
    if (lane == 0) { sE[wid] = Eel; sF[wid] = Efr; sI[wid] = Eirr; }
    __syncthreads();
    if (threadIdx.x == 0) {
        atomicAdd(&out[0], sE[0] + sE[1] + sE[2] + sE[3]);
        atomicAdd(&out[1], sF[0] + sF[1] + sF[2] + sF[3]);
        atomicAdd(&out[2], sI[0] + sI[1] + sI[2] + sI[3]);
    }
}

extern "C" void kernel_launch(void* const* d_in, const int* in_sizes, int n_in,
                              void* d_out, int out_size, void* d_ws, size_t ws_size,
                              hipStream_t stream) {
    const float* u      = (const float*)d_in[0];
    const float* v      = (const float*)d_in[1];
    const float* c      = (const float*)d_in[2];
    const float* prev_c = (const float*)d_in[3];
    const int*   conn   = (const int*)d_in[4];
    const float* Nf     = (const float*)d_in[5];
    const float* dNdx   = (const float*)d_in[6];
    const float* B      = (const float*)d_in[7];
    const float* vol    = (const float*)d_in[8];
    float* out = (float*)d_out;

    hipMemsetAsync(out, 0, 3 * sizeof(float), stream);

    fused_energy<<<NTHREADS / BLK, BLK, 0, stream>>>(
        u, v, c, prev_c, conn, Nf, dNdx, B, vol, out);
}